// Round 1
// baseline (1452.657 us; speedup 1.0000x reference)
//
#include <hip/hip_runtime.h>
#include <hip/hip_bf16.h>

#define L_LAYERS 4
#define D_MODEL 768
#define SEQ 1024
#define BATCH 2
#define NHEAD 12
#define HDIM 64
#define DFF_DIM 3072
#define VOCAB 32000
#define MROWS (BATCH*SEQ)                      // 2048
#define QKV_PLANE (NHEAD*BATCH*SEQ*HDIM)       // 24*1024*64 = 1572864

typedef __attribute__((ext_vector_type(8))) short bfrag8;   // 8 bf16 in 4 VGPRs
typedef __attribute__((ext_vector_type(4))) float facc4;    // MFMA accumulator

#define EPI_PLAIN 0
#define EPI_BIAS 1
#define EPI_GELU_BF16 2
#define EPI_QKV 3

__device__ __forceinline__ void gld_lds16(const __hip_bfloat16* g, __hip_bfloat16* l) {
    __builtin_amdgcn_global_load_lds((const __attribute__((address_space(1))) void*)g,
                                     (__attribute__((address_space(3))) void*)l, 16, 0, 0);
}

// ---------------- weight transpose + cast: src fp32 [K,N] -> dst bf16 [N,K] ----------------
__global__ __launch_bounds__(256) void transpose_cast(
    const float* __restrict__ src, __hip_bfloat16* __restrict__ dst,
    const int K, const int N, const long sL, const long dL)
{
    __shared__ float tile[32][33];
    const int z = blockIdx.z;
    const float* s = src + (long)z * sL;
    __hip_bfloat16* d = dst + (long)z * dL;
    const int bx = blockIdx.x * 32;   // N block
    const int by = blockIdx.y * 32;   // K block
    const int tx = threadIdx.x, ty = threadIdx.y;
    #pragma unroll
    for (int r = 0; r < 4; ++r)
        tile[ty + r*8][tx] = s[(long)(by + ty + r*8) * N + bx + tx];
    __syncthreads();
    #pragma unroll
    for (int r = 0; r < 4; ++r)
        d[(long)(bx + ty + r*8) * K + by + tx] = __float2bfloat16(tile[tx][ty + r*8]);
}

// ---------------- embedding + sinusoidal PE -> h fp32, hb bf16 ----------------
__global__ __launch_bounds__(256) void embed_k(
    const int* __restrict__ xids, const float* __restrict__ emb,
    float* __restrict__ h, __hip_bfloat16* __restrict__ hb)
{
    const int row = blockIdx.x, t = threadIdx.x;
    const int tok = xids[row];
    const int spos = row & (SEQ - 1);
    const long base = (long)row * D_MODEL;
    const long ebase = (long)tok * D_MODEL;
    #pragma unroll
    for (int j = 0; j < 3; ++j) {
        const int d = j*256 + t;
        const int i = d >> 1;
        const float ang = (float)spos * expf(-(float)(2*i) * (9.210340371976184f / 768.0f));
        const float pe = (d & 1) ? cosf(ang) : sinf(ang);
        const float v = emb[ebase + d] + pe;
        h[base + d] = v;
        hb[base + d] = __float2bfloat16(v);
    }
}

// ---------------- residual add + LayerNorm -> h fp32 (in place), hb bf16 ----------------
__global__ __launch_bounds__(256) void ln_residual(
    float* __restrict__ h, __hip_bfloat16* __restrict__ hb,
    const float* __restrict__ delta,
    const float* __restrict__ sc, const float* __restrict__ bi)
{
    const int row = blockIdx.x, t = threadIdx.x;
    const long base = (long)row * D_MODEL;
    float x[3];
    float s1 = 0.f, s2 = 0.f;
    #pragma unroll
    for (int j = 0; j < 3; ++j) {
        const int d = j*256 + t;
        const float v = h[base + d] + delta[base + d];
        x[j] = v; s1 += v; s2 += v*v;
    }
    #pragma unroll
    for (int off = 32; off >= 1; off >>= 1) {
        s1 += __shfl_xor(s1, off);
        s2 += __shfl_xor(s2, off);
    }
    __shared__ float r1[4], r2[4];
    const int wv = t >> 6;
    if ((t & 63) == 0) { r1[wv] = s1; r2[wv] = s2; }
    __syncthreads();
    s1 = r1[0] + r1[1] + r1[2] + r1[3];
    s2 = r2[0] + r2[1] + r2[2] + r2[3];
    const float mean = s1 * (1.0f/768.0f);
    const float var  = s2 * (1.0f/768.0f) - mean*mean;
    const float inv  = rsqrtf(var + 1e-5f);
    #pragma unroll
    for (int j = 0; j < 3; ++j) {
        const int d = j*256 + t;
        const float y = (x[j] - mean) * inv * sc[d] + bi[d];
        h[base + d] = y;
        hb[base + d] = __float2bfloat16(y);
    }
}

// ---------------- generic bf16 MFMA GEMM: C[M,N] = A[M,K] * Bt[N,K]^T (+epilogue) ----------------
// 128x128 tile, BK=32, 256 threads (4 waves, 2x2), m97-style global_load_lds staging.
__global__ __launch_bounds__(256) void gemm_bt(
    const __hip_bfloat16* __restrict__ A,
    const __hip_bfloat16* __restrict__ Bt,
    const float* __restrict__ bias,
    float* __restrict__ outf,
    __hip_bfloat16* __restrict__ outb,
    const int N, const int K, const int epi)
{
    __shared__ __hip_bfloat16 As[128*32];
    __shared__ __hip_bfloat16 Bs[128*32];
    const int tid = threadIdx.x;
    const int lane = tid & 63, wv = tid >> 6;
    const int bm = blockIdx.y * 128, bn = blockIdx.x * 128;
    const int wm = (wv >> 1) * 64, wn = (wv & 1) * 64;
    const int fr = lane & 15, fq = lane >> 4;

    facc4 acc[4][4];
    #pragma unroll
    for (int i = 0; i < 4; ++i)
        #pragma unroll
        for (int j = 0; j < 4; ++j) { facc4 z = {0.f,0.f,0.f,0.f}; acc[i][j] = z; }

    // staging: wave wv owns tile rows [wv*32, wv*32+32), 2 issues of 16 rows each
    const int srow = wv*32 + (lane >> 2);
    const int scol = (lane & 3) * 8;
    const __hip_bfloat16* Ag = A  + (long)(bm + srow) * K + scol;
    const __hip_bfloat16* Bg = Bt + (long)(bn + srow) * K + scol;
    __hip_bfloat16* Asw = As + wv*1024;
    __hip_bfloat16* Bsw = Bs + wv*1024;

    for (int k0 = 0; k0 < K; k0 += 32) {
        __syncthreads();
        gld_lds16(Ag + k0,                 Asw);
        gld_lds16(Ag + k0 + (long)16*K,    Asw + 512);
        gld_lds16(Bg + k0,                 Bsw);
        gld_lds16(Bg + k0 + (long)16*K,    Bsw + 512);
        __syncthreads();
        bfrag8 af[4], bf[4];
        #pragma unroll
        for (int i = 0; i < 4; ++i) af[i] = *(const bfrag8*)(As + (wm + i*16 + fr)*32 + fq*8);
        #pragma unroll
        for (int j = 0; j < 4; ++j) bf[j] = *(const bfrag8*)(Bs + (wn + j*16 + fr)*32 + fq*8);
        #pragma unroll
        for (int i = 0; i < 4; ++i)
            #pragma unroll
            for (int j = 0; j < 4; ++j)
                acc[i][j] = __builtin_amdgcn_mfma_f32_16x16x32_bf16(af[i], bf[j], acc[i][j], 0, 0, 0);
    }

    // epilogue: C elem (i,j,r): row = bm+wm+i*16+fq*4+r, col = bn+wn+j*16+fr
    if (epi == EPI_QKV) {
        __hip_bfloat16* qo = outb;
        __hip_bfloat16* ko = outb + QKV_PLANE;
        __hip_bfloat16* vo = outb + 2*QKV_PLANE;
        #pragma unroll
        for (int i = 0; i < 4; ++i) {
            #pragma unroll
            for (int j = 0; j < 4; ++j) {
                const int gn = bn + wn + j*16 + fr;
                const int which = gn / D_MODEL;
                const int nn = gn - which * D_MODEL;
                const int hh = nn >> 6, dd = nn & 63;
                #pragma unroll
                for (int r = 0; r < 4; ++r) {
                    const int gm = bm + wm + i*16 + fq*4 + r;
                    const int bidx = gm >> 10, si = gm & (SEQ-1);
                    const long bh = (long)bidx * NHEAD + hh;
                    const __hip_bfloat16 bv = __float2bfloat16(acc[i][j][r]);
                    if (which == 0)      qo[(bh*SEQ + si)*HDIM + dd] = bv;   // Q planar [bh][s][d]
                    else if (which == 1) ko[(bh*SEQ + si)*HDIM + dd] = bv;   // K planar [bh][s][d]
                    else                 vo[(bh*HDIM + dd)*SEQ + si] = bv;   // V transposed [bh][d][s]
                }
            }
        }
    } else if (epi == EPI_GELU_BF16) {
        #pragma unroll
        for (int i = 0; i < 4; ++i)
            #pragma unroll
            for (int j = 0; j < 4; ++j) {
                const int gn = bn + wn + j*16 + fr;
                const float bb = bias[gn];
                #pragma unroll
                for (int r = 0; r < 4; ++r) {
                    const int gm = bm + wm + i*16 + fq*4 + r;
                    const float v = acc[i][j][r] + bb;
                    const float g = 0.5f * v * (1.0f + erff(v * 0.70710678118f));
                    outb[(long)gm * N + gn] = __float2bfloat16(g);
                }
            }
    } else if (epi == EPI_BIAS) {
        #pragma unroll
        for (int i = 0; i < 4; ++i)
            #pragma unroll
            for (int j = 0; j < 4; ++j) {
                const int gn = bn + wn + j*16 + fr;
                const float bb = bias[gn];
                #pragma unroll
                for (int r = 0; r < 4; ++r) {
                    const int gm = bm + wm + i*16 + fq*4 + r;
                    outf[(long)gm * N + gn] = acc[i][j][r] + bb;
                }
            }
    } else {
        #pragma unroll
        for (int i = 0; i < 4; ++i)
            #pragma unroll
            for (int j = 0; j < 4; ++j) {
                const int gn = bn + wn + j*16 + fr;
                #pragma unroll
                for (int r = 0; r < 4; ++r) {
                    const int gm = bm + wm + i*16 + fq*4 + r;
                    outf[(long)gm * N + gn] = acc[i][j][r];
                }
            }
    }
}

// ---------------- fused causal attention (strict mask k<q, exp/(sum+1e-9) softmax) ----------------
// grid (S/64, B*H); block 256 = 4 waves; wave w owns q rows [q0+16w, q0+16w+16)
#define KS_STRIDE 80   // 32 k-rows x 64 d, padded (160B rows, 16B aligned)
#define VS_STRIDE 40   // 64 d-rows x 32 k, padded (80B rows)
#define PS_STRIDE 40   // per-wave P: 16 q x 32 k, padded
__global__ __launch_bounds__(256) void attn_flash(
    const __hip_bfloat16* __restrict__ Q,   // [BH][S][64]
    const __hip_bfloat16* __restrict__ Kp,  // [BH][S][64]
    const __hip_bfloat16* __restrict__ Vt,  // [BH][64][S]
    __hip_bfloat16* __restrict__ avo)       // [2048][768] bf16 (A for Wo GEMM)
{
    __shared__ __hip_bfloat16 Ks[32*KS_STRIDE];
    __shared__ __hip_bfloat16 Vs[64*VS_STRIDE];
    __shared__ __hip_bfloat16 Ps[4][16*PS_STRIDE];
    const int tid = threadIdx.x;
    const int lane = tid & 63, wv = tid >> 6;
    const int fr = lane & 15, fq = lane >> 4;
    const int q0 = blockIdx.x * 64;
    const int bh = blockIdx.y;
    const int qrow = q0 + wv*16;

    // Q fragments straight from global (A layout: m=fr, k=fq*8+j)
    const __hip_bfloat16* qp = Q + ((long)bh*SEQ + qrow + fr)*HDIM + fq*8;
    const bfrag8 aq0 = *(const bfrag8*)(qp);
    const bfrag8 aq1 = *(const bfrag8*)(qp + 32);

    facc4 accv[4];
    #pragma unroll
    for (int n = 0; n < 4; ++n) { facc4 z = {0.f,0.f,0.f,0.f}; accv[n] = z; }
    float denom[4] = {0.f, 0.f, 0.f, 0.f};

    const __hip_bfloat16* kg = Kp + ((long)bh*SEQ + (tid>>3))*HDIM + (tid&7)*8;
    const __hip_bfloat16* vg = Vt + ((long)bh*HDIM + (tid>>2))*SEQ + (tid&3)*8;
    __hip_bfloat16* ksw = Ks + (tid>>3)*KS_STRIDE + (tid&7)*8;
    __hip_bfloat16* vsw = Vs + (tid>>2)*VS_STRIDE + (tid&3)*8;

    const int kend = q0 + 64;   // strict mask: max needed k is q0+62
    for (int k0 = 0; k0 < kend; k0 += 32) {
        __syncthreads();
        *(bfrag8*)ksw = *(const bfrag8*)(kg + (long)k0 * HDIM);
        *(bfrag8*)vsw = *(const bfrag8*)(vg + k0);
        __syncthreads();
        #pragma unroll
        for (int t = 0; t < 2; ++t) {
            const int koff = t*16;
            const bfrag8 bk0 = *(const bfrag8*)(Ks + (koff + fr)*KS_STRIDE + fq*8);
            const bfrag8 bk1 = *(const bfrag8*)(Ks + (koff + fr)*KS_STRIDE + 32 + fq*8);
            facc4 sc = {0.f,0.f,0.f,0.f};
            sc = __builtin_amdgcn_mfma_f32_16x16x32_bf16(aq0, bk0, sc, 0, 0, 0);
            sc = __builtin_amdgcn_mfma_f32_16x16x32_bf16(aq1, bk1, sc, 0, 0, 0);
            const int ki = k0 + koff + fr;
            #pragma unroll
            for (int r = 0; r < 4; ++r) {
                const int qi = qrow + fq*4 + r;
                const float e = (ki < qi) ? __expf(sc[r] * 0.125f) : 0.f;
                denom[r] += e;
                Ps[wv][(fq*4 + r)*PS_STRIDE + koff + fr] = __float2bfloat16(e);
            }
        }
        __syncthreads();
        const bfrag8 ap = *(const bfrag8*)(&Ps[wv][fr*PS_STRIDE + fq*8]);
        #pragma unroll
        for (int n = 0; n < 4; ++n) {
            const bfrag8 bv = *(const bfrag8*)(Vs + (n*16 + fr)*VS_STRIDE + fq*8);
            accv[n] = __builtin_amdgcn_mfma_f32_16x16x32_bf16(ap, bv, accv[n], 0, 0, 0);
        }
    }

    // row sums: reduce denom across the 16 lanes of each row group
    #pragma unroll
    for (int r = 0; r < 4; ++r) {
        #pragma unroll
        for (int off = 1; off < 16; off <<= 1) denom[r] += __shfl_xor(denom[r], off);
    }
    const int bidx = bh / NHEAD, hh = bh % NHEAD;
    #pragma unroll
    for (int n = 0; n < 4; ++n) {
        #pragma unroll
        for (int r = 0; r < 4; ++r) {
            const int qi = qrow + fq*4 + r;
            const int dd = n*16 + fr;
            const float o = accv[n][r] / (denom[r] + 1e-9f);
            avo[((long)(bidx*SEQ + qi))*D_MODEL + hh*HDIM + dd] = __float2bfloat16(o);
        }
    }
}

extern "C" void kernel_launch(void* const* d_in, const int* in_sizes, int n_in,
                              void* d_out, int out_size, void* d_ws, size_t ws_size,
                              hipStream_t stream) {
    const int*   x    = (const int*)d_in[0];
    const float* emb  = (const float*)d_in[1];
    const float* Wq   = (const float*)d_in[2];
    const float* Wk   = (const float*)d_in[3];
    const float* Wv   = (const float*)d_in[4];
    const float* Wo   = (const float*)d_in[5];
    const float* ln1s = (const float*)d_in[6];
    const float* ln1b = (const float*)d_in[7];
    const float* W1   = (const float*)d_in[8];
    const float* b1   = (const float*)d_in[9];
    const float* W2   = (const float*)d_in[10];
    const float* b2   = (const float*)d_in[11];
    const float* ln2s = (const float*)d_in[12];
    const float* ln2b = (const float*)d_in[13];
    const float* lmW  = (const float*)d_in[14];
    const float* lmb  = (const float*)d_in[15];
    float* out = (float*)d_out;

    char* wsp = (char*)d_ws;
    size_t off = 0;
    auto take = [&](size_t bytes) -> char* {
        char* p = wsp + off;
        off += (bytes + 255) & ~(size_t)255;
        return p;
    };
    __hip_bfloat16* wqkvT = (__hip_bfloat16*)take((size_t)L_LAYERS*2304*768*2); // fused [2304,768] per layer
    __hip_bfloat16* woT   = (__hip_bfloat16*)take((size_t)L_LAYERS*768*768*2);
    __hip_bfloat16* w1T   = (__hip_bfloat16*)take((size_t)L_LAYERS*3072*768*2);
    __hip_bfloat16* w2T   = (__hip_bfloat16*)take((size_t)L_LAYERS*768*3072*2);
    __hip_bfloat16* lmT   = (__hip_bfloat16*)take((size_t)VOCAB*768*2);
    float*          hbuf  = (float*)take((size_t)MROWS*D_MODEL*4);
    __hip_bfloat16* hb    = (__hip_bfloat16*)take((size_t)MROWS*D_MODEL*2);
    __hip_bfloat16* qkvb  = (__hip_bfloat16*)take((size_t)3*QKV_PLANE*2);
    __hip_bfloat16* avb   = (__hip_bfloat16*)take((size_t)MROWS*D_MODEL*2);
    __hip_bfloat16* ffb   = (__hip_bfloat16*)take((size_t)MROWS*DFF_DIM*2);
    float*          tmp   = (float*)take((size_t)MROWS*D_MODEL*4);

    dim3 tb(32, 8);
    transpose_cast<<<dim3(24,24,4), tb, 0, stream>>>(Wq, wqkvT,              768, 768, (long)768*768, (long)2304*768);
    transpose_cast<<<dim3(24,24,4), tb, 0, stream>>>(Wk, wqkvT + 768*768,    768, 768, (long)768*768, (long)2304*768);
    transpose_cast<<<dim3(24,24,4), tb, 0, stream>>>(Wv, wqkvT + 2*768*768,  768, 768, (long)768*768, (long)2304*768);
    transpose_cast<<<dim3(24,24,4), tb, 0, stream>>>(Wo, woT,                768, 768, (long)768*768, (long)768*768);
    transpose_cast<<<dim3(96,24,4), tb, 0, stream>>>(W1, w1T,                768, 3072, (long)768*3072, (long)3072*768);
    transpose_cast<<<dim3(24,96,4), tb, 0, stream>>>(W2, w2T,                3072, 768, (long)3072*768, (long)768*3072);
    transpose_cast<<<dim3(1000,24,1), tb, 0, stream>>>(lmW, lmT,             768, VOCAB, 0, 0);

    embed_k<<<MROWS, 256, 0, stream>>>(x, emb, hbuf, hb);

    for (int l = 0; l < L_LAYERS; ++l) {
        gemm_bt<<<dim3(18,16), 256, 0, stream>>>(hb, wqkvT + (size_t)l*2304*768, nullptr,
                                                 nullptr, qkvb, 2304, 768, EPI_QKV);
        attn_flash<<<dim3(16,24), 256, 0, stream>>>(qkvb, qkvb + QKV_PLANE, qkvb + 2*QKV_PLANE, avb);
        gemm_bt<<<dim3(6,16), 256, 0, stream>>>(avb, woT + (size_t)l*768*768, nullptr,
                                                tmp, nullptr, 768, 768, EPI_PLAIN);
        ln_residual<<<MROWS, 256, 0, stream>>>(hbuf, hb, tmp, ln1s + l*768, ln1b + l*768);
        gemm_bt<<<dim3(24,16), 256, 0, stream>>>(hb, w1T + (size_t)l*3072*768, b1 + l*DFF_DIM,
                                                 nullptr, ffb, DFF_DIM, 768, EPI_GELU_BF16);
        gemm_bt<<<dim3(6,16), 256, 0, stream>>>(ffb, w2T + (size_t)l*768*3072, b2 + l*768,
                                                tmp, nullptr, 768, DFF_DIM, EPI_BIAS);
        ln_residual<<<MROWS, 256, 0, stream>>>(hbuf, hb, tmp, ln2s + l*768, ln2b + l*768);
    }
    gemm_bt<<<dim3(250,16), 256, 0, stream>>>(hb, lmT, lmb, out, nullptr, VOCAB, 768, EPI_BIAS);
}